// Round 15
// baseline (239.163 us; speedup 1.0000x reference)
//
#include <hip/hip_runtime.h>
#include <hip/hip_bf16.h>
#include <math.h>

// Problem constants
#define B_    256
#define L_    200
#define H_    256
#define MAXT  256
#define SIXH  1536
#define FOURH 1024
#define NPOS  (B_ * L_)   // 51200

typedef __attribute__((ext_vector_type(8))) short short8;
typedef __attribute__((ext_vector_type(4))) float f32x4;

typedef __attribute__((address_space(3))) void lds_void;
typedef const __attribute__((address_space(1))) void gbl_void;

#define ASM_BAR() asm volatile("s_barrier" ::: "memory")
#define VMCNT4()  asm volatile("s_waitcnt vmcnt(4)" ::: "memory")
#define VMCNT0()  asm volatile("s_waitcnt vmcnt(0)" ::: "memory")

__device__ __forceinline__ float bf16_bits_to_f32(unsigned short u) {
  unsigned int w = ((unsigned int)u) << 16;
  float f;
  __builtin_memcpy(&f, &w, 4);
  return f;
}

// ---------------------------------------------------------------------------
// fused_pre_tr: ONE launch, 5179 blocks x 256 threads.
//   blocks 0..255    : prefix-sum offsets, tpos scatter map, zero-pad x rows
//   blocks 256..2047 : weight transpose+bf16 (w1 -> w1t, w2 -> w2t)
//   blocks 2048..5178: table f32 -> bf16 conversion (16 rows per block)
// ---------------------------------------------------------------------------
__global__ void fused_pre_tr(const int* __restrict__ lengths,
                             const int* __restrict__ gids,
                             int* __restrict__ offsets,
                             int* __restrict__ tpos,
                             __hip_bfloat16* __restrict__ x,
                             const float* __restrict__ w1,
                             __hip_bfloat16* __restrict__ w1t,
                             const float* __restrict__ w2,
                             __hip_bfloat16* __restrict__ w2t,
                             const float* __restrict__ token_emb,
                             const float* __restrict__ tg_emb,
                             const float* __restrict__ g_emb,
                             unsigned short* __restrict__ tokb,
                             unsigned short* __restrict__ tgb,
                             unsigned short* __restrict__ gb) {
  int bid = blockIdx.x;
  int t = threadIdx.x;

  if (bid >= 2048) {
    // ---- table conversion: 16 rows/block, thread t -> row +t/16, cols (t%16)*16
    int row = (bid - 2048) * 16 + (t >> 4);
    if (row < 50082) {
      const float* src; unsigned short* dst; int r;
      if (row < 50000)      { src = token_emb; dst = tokb; r = row; }
      else if (row < 50065) { src = tg_emb;    dst = tgb;  r = row - 50000; }
      else                  { src = g_emb;     dst = gb;   r = row - 50065; }
      int c0 = (t & 15) * 16;
      const float4* s4 = (const float4*)(src + (size_t)r * 256 + c0);
      unsigned short* d = dst + (size_t)r * 256 + c0;
#pragma unroll
      for (int half = 0; half < 2; half++) {
        float4 va = s4[half * 2], vb = s4[half * 2 + 1];
        short8 pk;
        __hip_bfloat16 hh;
        hh = __float2bfloat16(va.x); pk[0] = *(short*)&hh;
        hh = __float2bfloat16(va.y); pk[1] = *(short*)&hh;
        hh = __float2bfloat16(va.z); pk[2] = *(short*)&hh;
        hh = __float2bfloat16(va.w); pk[3] = *(short*)&hh;
        hh = __float2bfloat16(vb.x); pk[4] = *(short*)&hh;
        hh = __float2bfloat16(vb.y); pk[5] = *(short*)&hh;
        hh = __float2bfloat16(vb.z); pk[6] = *(short*)&hh;
        hh = __float2bfloat16(vb.w); pk[7] = *(short*)&hh;
        *(short8*)(d + half * 8) = pk;
      }
    }
    return;
  }

  if (bid >= 256) {
    // ---- transpose part ----
    __shared__ float tile[32][33];
    int id = bid - 256;
    const float* in; __hip_bfloat16* out; int R, C, tc, tr;
    if (id < 1536) {
      in = w1; out = w1t; R = 1536; C = 1024; tc = id & 31; tr = id >> 5;
    } else {
      int j = id - 1536;
      in = w2; out = w2t; R = 1024; C = 256; tc = j & 7; tr = j >> 3;
    }
    int tx = t & 31, ty = t >> 5;
#pragma unroll
    for (int i = 0; i < 4; i++)
      tile[ty + i * 8][tx] =
          in[(size_t)(tr * 32 + ty + i * 8) * C + tc * 32 + tx];
    __syncthreads();
#pragma unroll
    for (int i = 0; i < 4; i++)
      out[(size_t)(tc * 32 + ty + i * 8) * R + tr * 32 + tx] =
          __float2bfloat16(tile[tx][ty + i * 8]);
    return;
  }

  // ---- pre part (block b = bid) ----
  int b = bid;
  int lane = t & 63, wv = t >> 6;

  int len_t = lengths[t];
  int s = len_t;
#pragma unroll
  for (int o = 1; o < 64; o <<= 1) {
    int v = __shfl_up(s, o);
    if (lane >= o) s += v;
  }
  __shared__ int wsum[4];
  __shared__ int all_off[257];
  if (lane == 63) wsum[wv] = s;
  __syncthreads();
  int pre = 0;
#pragma unroll
  for (int k = 0; k < 4; k++)
    if (k < wv) pre += wsum[k];
  s += pre;
  all_off[t] = s - len_t;
  if (t == 255) all_off[256] = s;
  __syncthreads();

  int base = all_off[b];
  int total = all_off[256];
  if (t == 0) {
    offsets[b] = base;
    if (b == 0) offsets[B_] = total;
  }

  // tpos for batch b
  __shared__ int g[L_];
  int len = lengths[b];
  for (int l = t; l < len; l += 256) g[l] = gids[b * L_ + l];
  __syncthreads();
  if (t == 0) {
    int nsep = 0;
    for (int l = 0; l + 1 < len; l++)
      if (g[l] != g[l + 1]) nsep++;
    int tot = len + nsep;
    int off = MAXT - tot;
    int sb = 0;
    for (int l = 0; l < len; l++) {
      int ti = off + l + sb;
      tpos[base + l] = (ti >= 0) ? (b * MAXT + ti) : -1;
      if (l + 1 < len && g[l] != g[l + 1]) sb++;
    }
  }

  // zero-pad x row (total + b) if within padded range
  int padded = (total + 255) & ~255;
  int row = total + b;
  if (row < padded) {
#pragma unroll
    for (int j = 0; j < 6; j++)
      x[(size_t)row * SIXH + j * 256 + t] = __float2bfloat16(0.0f);
  }
}

// ---------------------------------------------------------------------------
// Fused embedding gather + concat + LayerNorm -> x bf16 [row][1536]
// R15: gathers from BF16 tables (16 B/lane short8) — half the read volume.
// 192 threads (3 waves); thread handles 8 channels of table j.
// ---------------------------------------------------------------------------
__global__ void embed_ln_kernel(const int* __restrict__ tok0,
                                const int* __restrict__ tok1,
                                const int* __restrict__ tok2,
                                const int* __restrict__ tok3,
                                const int* __restrict__ tgap,
                                const int* __restrict__ gid,
                                const int* __restrict__ lengths,
                                const int* __restrict__ offsets,
                                const unsigned short* __restrict__ tokb,
                                const unsigned short* __restrict__ tgb,
                                const unsigned short* __restrict__ gb,
                                const float* __restrict__ gamma,
                                const float* __restrict__ beta,
                                __hip_bfloat16* __restrict__ xout) {
  int l = blockIdx.x, b = blockIdx.y;
  if (l >= lengths[b]) return;
  int pos = b * L_ + l;
  int row = offsets[b] + l;
  int t = threadIdx.x;        // 0..191
  int wv = t >> 6;            // 0..2
  int lane = t & 63;
  int j = wv * 2 + (lane >> 5);  // table 0..5
  int c8 = (lane & 31) * 8;      // channel base within table

  const unsigned short* tab;
  int idx;
  if (j == 0)      { tab = tokb; idx = tok0[pos]; }
  else if (j == 1) { tab = tokb; idx = tok1[pos]; }
  else if (j == 2) { tab = tokb; idx = tok2[pos]; }
  else if (j == 3) { tab = tokb; idx = tok3[pos]; }
  else if (j == 4) { tab = tgb;  idx = min(max(tgap[pos], 0), 64); }
  else             { tab = gb;   idx = gid[pos]; }

  short8 raw = *(const short8*)(tab + (size_t)idx * H_ + c8);
  float v[8];
#pragma unroll
  for (int i = 0; i < 8; i++) v[i] = bf16_bits_to_f32((unsigned short)raw[i]);

  float s = 0.f, q = 0.f;
#pragma unroll
  for (int i = 0; i < 8; i++) { s += v[i]; q += v[i] * v[i]; }
#pragma unroll
  for (int o = 32; o; o >>= 1) { s += __shfl_down(s, o); q += __shfl_down(q, o); }
  __shared__ float ps[3], pq[3];
  if (lane == 0) { ps[wv] = s; pq[wv] = q; }
  __syncthreads();
  float ts = ps[0] + ps[1] + ps[2];
  float tq = pq[0] + pq[1] + pq[2];
  float mu = ts * (1.0f / 1536.0f);
  float var = tq * (1.0f / 1536.0f) - mu * mu;
  float rstd = rsqrtf(var + 1e-5f);

  int cbase = j * 256 + c8;
  float4 gm0 = *(const float4*)&gamma[cbase];
  float4 gm1 = *(const float4*)&gamma[cbase + 4];
  float4 bt0 = *(const float4*)&beta[cbase];
  float4 bt1 = *(const float4*)&beta[cbase + 4];

  float y[8];
  y[0] = (v[0] - mu) * rstd * gm0.x + bt0.x;
  y[1] = (v[1] - mu) * rstd * gm0.y + bt0.y;
  y[2] = (v[2] - mu) * rstd * gm0.z + bt0.z;
  y[3] = (v[3] - mu) * rstd * gm0.w + bt0.w;
  y[4] = (v[4] - mu) * rstd * gm1.x + bt1.x;
  y[5] = (v[5] - mu) * rstd * gm1.y + bt1.y;
  y[6] = (v[6] - mu) * rstd * gm1.z + bt1.z;
  y[7] = (v[7] - mu) * rstd * gm1.w + bt1.w;

  short8 pk;
#pragma unroll
  for (int i = 0; i < 8; i++) {
    __hip_bfloat16 hh = __float2bfloat16(y[i]);
    pk[i] = *(short*)&hh;
  }
  *(short8*)&xout[(size_t)row * SIXH + cbase] = pk;
}

// ---------------------------------------------------------------------------
// GEMM1: R9 version verbatim (best measured: 102.6us, FETCH 64.7MB,
// 0 bank conflicts). Persistent, XCD-sibling-grouped, 256x256 tile, BK=64,
// 8 waves, 2-barrier K-loop, counted vmcnt(4), XOR-swizzled LDS.
// ---------------------------------------------------------------------------
__global__ __launch_bounds__(512, 2)
void gemm1_8ph(const __hip_bfloat16* __restrict__ A,
               const __hip_bfloat16* __restrict__ Bt,
               const float* __restrict__ bias,
               __hip_bfloat16* __restrict__ out,
               const int* __restrict__ total_ptr) {
  constexpr int K = SIXH;     // 1536
  constexpr int NT = K / 64;  // 24 K-tiles
  constexpr int N = FOURH;    // 1024

  extern __shared__ __align__(16) char lds[];

  int total = total_ptr[0];
  int padded = (total + 255) & ~255;
  int num_mt = padded >> 8;

  int bid = blockIdx.x;        // 0..255
  int xcd = bid & 7;
  int slot = bid >> 3;         // 0..31
  int nt = slot & 3;           // 0..3
  int mtb = slot >> 2;         // 0..7
  int n0 = nt * 256;

  int tid = threadIdx.x;
  int lane = tid & 63;
  int w = tid >> 6;
  int wave_m = w >> 2;
  int wave_n = w & 3;

  int r15 = lane & 15, g = lane >> 4;
  int slot_r = (((r15 & 1) << 2) | g) ^ (r15 >> 1);
  int lane_off = (r15 >> 1) * 128 + slot_r * 16;

  int s0 = (tid & 7) ^ ((tid >> 3) & 7);
  int scol = (s0 & 3) * 8;
  int row0 = ((tid >> 3) << 1) + (s0 >> 2);
  int ldst0 = w * 1024;

  float bv4[4];
#pragma unroll
  for (int ni = 0; ni < 4; ni++)
    bv4[ni] = bias[n0 + wave_n * 64 + ni * 16 + r15];

#define REGA(d, h) (lds + (d) * 65536 + (h) * 16384)
#define REGB(d, h) (lds + (d) * 65536 + 32768 + (h) * 16384)

#define STAGE(P, t0, kt, h, rb)                                                \
  do {                                                                         \
    __builtin_amdgcn_global_load_lds(                                          \
        (gbl_void*)((P) + (size_t)((t0) + row0) * K + (kt) * 64 + (h) * 32 +   \
                    scol),                                                     \
        (lds_void*)((rb) + ldst0), 16, 0, 0);                                  \
    __builtin_amdgcn_global_load_lds(                                          \
        (gbl_void*)((P) + (size_t)((t0) + row0 + 128) * K + (kt) * 64 +        \
                    (h) * 32 + scol),                                          \
        (lds_void*)((rb) + 8192 + ldst0), 16, 0, 0);                           \
  } while (0)

  for (int mt = xcd + 8 * mtb; mt < num_mt; mt += 64) {
    int m0 = mt * 256;

    f32x4 acc[8][4] = {};

    STAGE(A, m0, 0, 0, REGA(0, 0));
    STAGE(Bt, n0, 0, 0, REGB(0, 0));
    STAGE(A, m0, 0, 1, REGA(0, 1));
    STAGE(Bt, n0, 0, 1, REGB(0, 1));
    STAGE(A, m0, 1, 0, REGA(1, 0));
    STAGE(Bt, n0, 1, 0, REGB(1, 0));
    VMCNT4();
    ASM_BAR();

    for (int kt = 0; kt < NT; ++kt) {
      int d = kt & 1;
      int kc1 = (kt + 1 < NT) ? kt + 1 : NT - 1;
      int kc2 = (kt + 2 < NT) ? kt + 2 : NT - 1;
      char* A0 = REGA(d, 0); char* A1 = REGA(d, 1);
      char* B0 = REGB(d, 0); char* B1 = REGB(d, 1);
      char* An1 = REGA(d ^ 1, 1);
      char* Bn1 = REGB(d ^ 1, 1);

      short8 a[4], b[4];

      // ======== first half: kh0 (reads A0/B0; stages next-dbuf kh1) ========
#pragma unroll
      for (int ni = 0; ni < 4; ni++)
        b[ni] = *(const short8*)(B0 + (wave_n * 64 + ni * 16) * 64 + lane_off);
#pragma unroll
      for (int j = 0; j < 4; j++)
        a[j] = *(const short8*)(A0 + (wave_m * 128 + j * 16) * 64 + lane_off);
      STAGE(A, m0, kc1, 1, An1);
      __builtin_amdgcn_s_setprio(1);
#pragma unroll
      for (int j = 0; j < 4; j++)
#pragma unroll
        for (int ni = 0; ni < 4; ni++)
          acc[j][ni] = __builtin_amdgcn_mfma_f32_16x16x32_bf16(a[j], b[ni],
                                                               acc[j][ni], 0, 0, 0);
      __builtin_amdgcn_s_setprio(0);
#pragma unroll
      for (int j = 0; j < 4; j++)
        a[j] = *(const short8*)(A0 + (wave_m * 128 + (4 + j) * 16) * 64 + lane_off);
      STAGE(Bt, n0, kc1, 1, Bn1);
      __builtin_amdgcn_s_setprio(1);
#pragma unroll
      for (int j = 0; j < 4; j++)
#pragma unroll
        for (int ni = 0; ni < 4; ni++)
          acc[4 + j][ni] = __builtin_amdgcn_mfma_f32_16x16x32_bf16(
              a[j], b[ni], acc[4 + j][ni], 0, 0, 0);
      __builtin_amdgcn_s_setprio(0);
      ASM_BAR();  // bar_mid

      // ======== second half: kh1 (reads A1/B1; stages this-dbuf kh0) =======
#pragma unroll
      for (int ni = 0; ni < 4; ni++)
        b[ni] = *(const short8*)(B1 + (wave_n * 64 + ni * 16) * 64 + lane_off);
#pragma unroll
      for (int j = 0; j < 4; j++)
        a[j] = *(const short8*)(A1 + (wave_m * 128 + j * 16) * 64 + lane_off);
      STAGE(A, m0, kc2, 0, A0);
      __builtin_amdgcn_s_setprio(1);
#pragma unroll
      for (int j = 0; j < 4; j++)
#pragma unroll
        for (int ni = 0; ni < 4; ni++)
          acc[j][ni] = __builtin_amdgcn_mfma_f32_16x16x32_bf16(a[j], b[ni],
                                                               acc[j][ni], 0, 0, 0);
      __builtin_amdgcn_s_setprio(0);
#pragma unroll
      for (int j = 0; j < 4; j++)
        a[j] = *(const short8*)(A1 + (wave_m * 128 + (4 + j) * 16) * 64 + lane_off);
      STAGE(Bt, n0, kc2, 0, B0);
      __builtin_amdgcn_s_setprio(1);
#pragma unroll
      for (int j = 0; j < 4; j++)
#pragma unroll
        for (int ni = 0; ni < 4; ni++)
          acc[4 + j][ni] = __builtin_amdgcn_mfma_f32_16x16x32_bf16(
              a[j], b[ni], acc[4 + j][ni], 0, 0, 0);
      __builtin_amdgcn_s_setprio(0);
      VMCNT4();
      ASM_BAR();  // bar_end
    }
    VMCNT0();

    int r0 = g * 4;
#pragma unroll
    for (int mi = 0; mi < 8; mi++)
#pragma unroll
      for (int ni = 0; ni < 4; ni++) {
        int col = n0 + wave_n * 64 + ni * 16 + r15;
        float bv = bv4[ni];
#pragma unroll
        for (int r = 0; r < 4; r++) {
          int row = m0 + wave_m * 128 + mi * 16 + r0 + r;
          float v = acc[mi][ni][r] + bv;
          v = v / (1.0f + __expf(-v));  // silu
          out[(size_t)row * N + col] = __float2bfloat16(v);
        }
      }
  }
#undef STAGE
#undef REGA
#undef REGB
}

// ---------------------------------------------------------------------------
// GEMM2 wide (R12 verbatim): 128 rows x full N=256, 8 waves of 64x64,
// fused scatter epilogue into d_out.
// ---------------------------------------------------------------------------
__global__ __launch_bounds__(512, 2)
void gemm2_wide(const __hip_bfloat16* __restrict__ A,
                const __hip_bfloat16* __restrict__ Bt,
                const float* __restrict__ bias,
                const int* __restrict__ tpos,
                const float* __restrict__ pos_emb,
                float* __restrict__ out,
                const int* __restrict__ total_ptr) {
  constexpr int K = FOURH;  // 1024
  int m0 = blockIdx.x * 128;
  int total = total_ptr[0];
  int padded = (total + 127) & ~127;
  if (m0 >= padded) return;

  __shared__ __hip_bfloat16 As[128 * 64];  // 16KB
  __shared__ __hip_bfloat16 Bs[256 * 64];  // 32KB
  int tid = threadIdx.x;
  int lane = tid & 63, w = tid >> 6;
  int wave_m = w >> 2;  // 0..1
  int wave_n = w & 3;   // 0..3
  int wm = wave_m * 64, wn = wave_n * 64;

  int srow = lane >> 3;
  int scol = (lane & 7) * 8;
  int r15 = lane & 15, g = lane >> 4;

  f32x4 acc[4][4] = {};

  for (int k0 = 0; k0 < K; k0 += 64) {
#pragma unroll
    for (int i = 0; i < 2; i++) {
      int c = w * 2 + i;
      int row = c * 8 + srow;
      __builtin_amdgcn_global_load_lds(
          (gbl_void*)&A[(size_t)(m0 + row) * K + k0 + scol],
          (lds_void*)(As + c * 512), 16, 0, 0);
    }
#pragma unroll
    for (int i = 0; i < 4; i++) {
      int c = w * 4 + i;
      int row = c * 8 + srow;
      __builtin_amdgcn_global_load_lds(
          (gbl_void*)&Bt[(size_t)row * K + k0 + scol],
          (lds_void*)(Bs + c * 512), 16, 0, 0);
    }
    __syncthreads();
#pragma unroll
    for (int kk = 0; kk < 64; kk += 32) {
      short8 a[4], bb[4];
#pragma unroll
      for (int m = 0; m < 4; m++)
        a[m] = *(const short8*)&As[(wm + m * 16 + r15) * 64 + kk + 8 * g];
#pragma unroll
      for (int n = 0; n < 4; n++)
        bb[n] = *(const short8*)&Bs[(wn + n * 16 + r15) * 64 + kk + 8 * g];
#pragma unroll
      for (int m = 0; m < 4; m++)
#pragma unroll
        for (int n = 0; n < 4; n++)
          acc[m][n] = __builtin_amdgcn_mfma_f32_16x16x32_bf16(a[m], bb[n],
                                                              acc[m][n], 0, 0, 0);
    }
    __syncthreads();
  }

  int r0 = g * 4;
#pragma unroll
  for (int m = 0; m < 4; m++) {
#pragma unroll
    for (int r = 0; r < 4; r++) {
      int row = m0 + wm + m * 16 + r0 + r;
      if (row >= total) continue;
      int pa = tpos[row];
      if (pa < 0) continue;
      int p = pa & (MAXT - 1);
#pragma unroll
      for (int n = 0; n < 4; n++) {
        int col = wn + n * 16 + r15;
        float v = acc[m][n][r] + bias[col] + pos_emb[p * H_ + col];
        out[(size_t)pa * H_ + col] = v;
      }
    }
  }
}

// ---------------------------------------------------------------------------
// merge2: sep rows (sep_token + pos_emb), zero-fill empty positions, mm.
// ---------------------------------------------------------------------------
__global__ void merge2_kernel(const int* __restrict__ gids,
                              const int* __restrict__ lengths,
                              const float* __restrict__ sep_token,
                              const float* __restrict__ pos_emb,
                              float* __restrict__ out) {
  int b = blockIdx.x, t = threadIdx.x;
  __shared__ signed char src[MAXT];
  __shared__ int g[L_];
  __shared__ int sh_total;
  int len = lengths[b];
  src[t] = 0;
  for (int l = t; l < len; l += 256) g[l] = gids[b * L_ + l];
  __syncthreads();
  if (t == 0) {
    int nsep = 0;
    for (int l = 0; l + 1 < len; l++)
      if (g[l] != g[l + 1]) nsep++;
    int total = len + nsep;
    sh_total = total;
    int off = MAXT - total;
    int sb = 0;
    for (int l = 0; l < len; l++) {
      int ti = off + l + sb;
      if (ti >= 0) src[ti] = 2;
      if (l + 1 < len && g[l] != g[l + 1]) {
        if (ti + 1 >= 0) src[ti + 1] = 1;
        sb++;
      }
    }
  }
  __syncthreads();
  int total = sh_total;
  int mlen = min(total, MAXT);

  int q = t >> 6, lane = t & 63, c4 = lane * 4;
  float4 sep4 = *(const float4*)&sep_token[c4];
  float* orow = out + (size_t)b * MAXT * H_;
  for (int p0 = 0; p0 < MAXT; p0 += 4) {
    int p = p0 + q;
    int s = src[p];
    if (s == 2) continue;
    float4 v;
    if (s == 1) {
      float4 pe = *(const float4*)&pos_emb[p * H_ + c4];
      v.x = sep4.x + pe.x; v.y = sep4.y + pe.y;
      v.z = sep4.z + pe.z; v.w = sep4.w + pe.w;
    } else {
      v.x = 0.f; v.y = 0.f; v.z = 0.f; v.w = 0.f;
    }
    *(float4*)&orow[(size_t)p * H_ + c4] = v;
  }
  float* mm = out + (size_t)B_ * MAXT * H_;
  mm[b * MAXT + t] = (t >= MAXT - mlen) ? 1.0f : 0.0f;
}

// ---------------------------------------------------------------------------
// launch
// ---------------------------------------------------------------------------
extern "C" void kernel_launch(void* const* d_in, const int* in_sizes, int n_in,
                              void* d_out, int out_size, void* d_ws,
                              size_t ws_size, hipStream_t stream) {
  const int* tok0 = (const int*)d_in[0];
  const int* tok1 = (const int*)d_in[1];
  const int* tok2 = (const int*)d_in[2];
  const int* tok3 = (const int*)d_in[3];
  const int* tgap = (const int*)d_in[4];
  const int* gid  = (const int*)d_in[5];
  const int* lengths = (const int*)d_in[6];
  const float* token_emb = (const float*)d_in[7];
  const float* gamma = (const float*)d_in[8];
  const float* beta  = (const float*)d_in[9];
  const float* w1 = (const float*)d_in[10];
  const float* b1 = (const float*)d_in[11];
  const float* w2 = (const float*)d_in[12];
  const float* b2 = (const float*)d_in[13];
  const float* tg_emb = (const float*)d_in[14];
  const float* g_emb  = (const float*)d_in[15];
  const float* pos_emb = (const float*)d_in[16];
  const float* sep_tok = (const float*)d_in[17];

  // workspace layout (bytes):
  //   x     bf16 [<=51200][1536] @ 0          (157,286,400)
  //   h     bf16 [<=51200][1024] @ 157286400  (104,857,600)
  //     tokb bf16 [50000][256]   @ 235929600  (25,600,000)  [aliases h tail:
  //     tgb  bf16 [65][256]      @ 261529600  (    33,280)   written by pre,
  //     gb   bf16 [17][256]      @ 261562880  (     8,704)   read by embed_ln,
  //                                                          dead before gemm1
  //                                                          overwrites h]
  //   w1t   bf16 [1024][1536]    @ 262144000  (  3,145,728)
  //   w2t   bf16 [256][1024]     @ 265289728  (    524,288)
  //   offsets int[257]           @ 265814016  (      1,028)
  //   tpos  int  [<=51200]       @ 265815044  (    204,800)
  const size_t NEEDED = 266019844;
  if (ws_size < NEEDED) return;

  char* ws = (char*)d_ws;
  __hip_bfloat16* x = (__hip_bfloat16*)ws;
  __hip_bfloat16* h = (__hip_bfloat16*)(ws + 157286400);
  unsigned short* tokb = (unsigned short*)(ws + 235929600);
  unsigned short* tgb  = (unsigned short*)(ws + 261529600);
  unsigned short* gb   = (unsigned short*)(ws + 261562880);
  __hip_bfloat16* w1t = (__hip_bfloat16*)(ws + 262144000);
  __hip_bfloat16* w2t = (__hip_bfloat16*)(ws + 265289728);
  int* offsets = (int*)(ws + 265814016);
  int* tpos = (int*)(ws + 265815044);

  fused_pre_tr<<<5179, 256, 0, stream>>>(lengths, gid, offsets, tpos, x, w1,
                                         w1t, w2, w2t, token_emb, tg_emb,
                                         g_emb, tokb, tgb, gb);

  embed_ln_kernel<<<dim3(L_, B_), 192, 0, stream>>>(
      tok0, tok1, tok2, tok3, tgap, gid, lengths, offsets, tokb, tgb, gb,
      gamma, beta, x);

  hipFuncSetAttribute((const void*)gemm1_8ph,
                      hipFuncAttributeMaxDynamicSharedMemorySize, 131072);
  gemm1_8ph<<<256, 512, 131072, stream>>>(x, w1t, b1, h, offsets + B_);

  gemm2_wide<<<NPOS / 128, 512, 0, stream>>>(h, w2t, b2, tpos, pos_emb,
                                             (float*)d_out, offsets + B_);

  merge2_kernel<<<B_, 256, 0, stream>>>(gid, lengths, sep_tok, pos_emb,
                                        (float*)d_out);
}

// Round 16
// 231.507 us; speedup vs baseline: 1.0331x; 1.0331x over previous
//
#include <hip/hip_runtime.h>
#include <hip/hip_bf16.h>
#include <math.h>

// Problem constants
#define B_    256
#define L_    200
#define H_    256
#define MAXT  256
#define SIXH  1536
#define FOURH 1024
#define NPOS  (B_ * L_)   // 51200

typedef __attribute__((ext_vector_type(8))) short short8;
typedef __attribute__((ext_vector_type(4))) float f32x4;

typedef __attribute__((address_space(3))) void lds_void;
typedef const __attribute__((address_space(1))) void gbl_void;

#define ASM_BAR() asm volatile("s_barrier" ::: "memory")
#define VMCNT4()  asm volatile("s_waitcnt vmcnt(4)" ::: "memory")
#define VMCNT0()  asm volatile("s_waitcnt vmcnt(0)" ::: "memory")

// ---------------------------------------------------------------------------
// fused_pre_tr: ONE launch, 2048 blocks x 256 threads.
//   blocks 0..255   : prefix-sum offsets, tpos scatter map, zero-pad x rows
//   blocks 256..2047: weight transpose+bf16 (w1 -> w1t, w2 -> w2t)
// ---------------------------------------------------------------------------
__global__ void fused_pre_tr(const int* __restrict__ lengths,
                             const int* __restrict__ gids,
                             int* __restrict__ offsets,
                             int* __restrict__ tpos,
                             __hip_bfloat16* __restrict__ x,
                             const float* __restrict__ w1,
                             __hip_bfloat16* __restrict__ w1t,
                             const float* __restrict__ w2,
                             __hip_bfloat16* __restrict__ w2t) {
  int bid = blockIdx.x;
  int t = threadIdx.x;

  if (bid >= 256) {
    // ---- transpose part ----
    __shared__ float tile[32][33];
    int id = bid - 256;
    const float* in; __hip_bfloat16* out; int R, C, tc, tr;
    if (id < 1536) {
      in = w1; out = w1t; R = 1536; C = 1024; tc = id & 31; tr = id >> 5;
    } else {
      int j = id - 1536;
      in = w2; out = w2t; R = 1024; C = 256; tc = j & 7; tr = j >> 3;
    }
    int tx = t & 31, ty = t >> 5;
#pragma unroll
    for (int i = 0; i < 4; i++)
      tile[ty + i * 8][tx] =
          in[(size_t)(tr * 32 + ty + i * 8) * C + tc * 32 + tx];
    __syncthreads();
#pragma unroll
    for (int i = 0; i < 4; i++)
      out[(size_t)(tc * 32 + ty + i * 8) * R + tr * 32 + tx] =
          __float2bfloat16(tile[tx][ty + i * 8]);
    return;
  }

  // ---- pre part (block b = bid) ----
  int b = bid;
  int lane = t & 63, wv = t >> 6;

  int len_t = lengths[t];
  int s = len_t;
#pragma unroll
  for (int o = 1; o < 64; o <<= 1) {
    int v = __shfl_up(s, o);
    if (lane >= o) s += v;
  }
  __shared__ int wsum[4];
  __shared__ int all_off[257];
  if (lane == 63) wsum[wv] = s;
  __syncthreads();
  int pre = 0;
#pragma unroll
  for (int k = 0; k < 4; k++)
    if (k < wv) pre += wsum[k];
  s += pre;
  all_off[t] = s - len_t;
  if (t == 255) all_off[256] = s;
  __syncthreads();

  int base = all_off[b];
  int total = all_off[256];
  if (t == 0) {
    offsets[b] = base;
    if (b == 0) offsets[B_] = total;
  }

  // tpos for batch b
  __shared__ int g[L_];
  int len = lengths[b];
  for (int l = t; l < len; l += 256) g[l] = gids[b * L_ + l];
  __syncthreads();
  if (t == 0) {
    int nsep = 0;
    for (int l = 0; l + 1 < len; l++)
      if (g[l] != g[l + 1]) nsep++;
    int tot = len + nsep;
    int off = MAXT - tot;
    int sb = 0;
    for (int l = 0; l < len; l++) {
      int ti = off + l + sb;
      tpos[base + l] = (ti >= 0) ? (b * MAXT + ti) : -1;
      if (l + 1 < len && g[l] != g[l + 1]) sb++;
    }
  }

  // zero-pad x row (total + b) if within padded range
  int padded = (total + 255) & ~255;
  int row = total + b;
  if (row < padded) {
#pragma unroll
    for (int j = 0; j < 6; j++)
      x[(size_t)row * SIXH + j * 256 + t] = __float2bfloat16(0.0f);
  }
}

// ---------------------------------------------------------------------------
// Fused embedding gather + concat + LayerNorm -> x bf16 [row][1536]
// 192 threads (3 waves); thread handles 8 channels of table
// j = wv*2 + (lane>>5); two float4 loads, one 16B bf16x8 store (G13).
// ---------------------------------------------------------------------------
__global__ void embed_ln_kernel(const int* __restrict__ tok0,
                                const int* __restrict__ tok1,
                                const int* __restrict__ tok2,
                                const int* __restrict__ tok3,
                                const int* __restrict__ tgap,
                                const int* __restrict__ gid,
                                const int* __restrict__ lengths,
                                const int* __restrict__ offsets,
                                const float* __restrict__ token_emb,
                                const float* __restrict__ tg_emb,
                                const float* __restrict__ g_emb,
                                const float* __restrict__ gamma,
                                const float* __restrict__ beta,
                                __hip_bfloat16* __restrict__ xout) {
  int l = blockIdx.x, b = blockIdx.y;
  if (l >= lengths[b]) return;
  int pos = b * L_ + l;
  int row = offsets[b] + l;
  int t = threadIdx.x;        // 0..191
  int wv = t >> 6;            // 0..2
  int lane = t & 63;
  int j = wv * 2 + (lane >> 5);  // table 0..5
  int c8 = (lane & 31) * 8;      // channel base within table

  const float* tab;
  int idx;
  if (j == 0)      { tab = token_emb; idx = tok0[pos]; }
  else if (j == 1) { tab = token_emb; idx = tok1[pos]; }
  else if (j == 2) { tab = token_emb; idx = tok2[pos]; }
  else if (j == 3) { tab = token_emb; idx = tok3[pos]; }
  else if (j == 4) { tab = tg_emb;    idx = min(max(tgap[pos], 0), 64); }
  else             { tab = g_emb;     idx = gid[pos]; }

  const float* src = tab + (size_t)idx * H_ + c8;
  float4 v0 = *(const float4*)src;
  float4 v1 = *(const float4*)(src + 4);

  float s = v0.x + v0.y + v0.z + v0.w + v1.x + v1.y + v1.z + v1.w;
  float q = v0.x * v0.x + v0.y * v0.y + v0.z * v0.z + v0.w * v0.w +
            v1.x * v1.x + v1.y * v1.y + v1.z * v1.z + v1.w * v1.w;
#pragma unroll
  for (int o = 32; o; o >>= 1) { s += __shfl_down(s, o); q += __shfl_down(q, o); }
  __shared__ float ps[3], pq[3];
  if (lane == 0) { ps[wv] = s; pq[wv] = q; }
  __syncthreads();
  float ts = ps[0] + ps[1] + ps[2];
  float tq = pq[0] + pq[1] + pq[2];
  float mu = ts * (1.0f / 1536.0f);
  float var = tq * (1.0f / 1536.0f) - mu * mu;
  float rstd = rsqrtf(var + 1e-5f);

  int cbase = j * 256 + c8;
  float4 gm0 = *(const float4*)&gamma[cbase];
  float4 gm1 = *(const float4*)&gamma[cbase + 4];
  float4 bt0 = *(const float4*)&beta[cbase];
  float4 bt1 = *(const float4*)&beta[cbase + 4];

  float y[8];
  y[0] = (v0.x - mu) * rstd * gm0.x + bt0.x;
  y[1] = (v0.y - mu) * rstd * gm0.y + bt0.y;
  y[2] = (v0.z - mu) * rstd * gm0.z + bt0.z;
  y[3] = (v0.w - mu) * rstd * gm0.w + bt0.w;
  y[4] = (v1.x - mu) * rstd * gm1.x + bt1.x;
  y[5] = (v1.y - mu) * rstd * gm1.y + bt1.y;
  y[6] = (v1.z - mu) * rstd * gm1.z + bt1.z;
  y[7] = (v1.w - mu) * rstd * gm1.w + bt1.w;

  short8 pk;
#pragma unroll
  for (int i = 0; i < 8; i++) {
    __hip_bfloat16 hh = __float2bfloat16(y[i]);
    pk[i] = *(short*)&hh;
  }
  *(short8*)&xout[(size_t)row * SIXH + cbase] = pk;
}

// ---------------------------------------------------------------------------
// GEMM1: R9 version verbatim (best measured: 102.6us, FETCH 64.7MB,
// 0 bank conflicts). Persistent, XCD-sibling-grouped, 256x256 tile, BK=64,
// 8 waves, 2-barrier K-loop, counted vmcnt(4), XOR-swizzled LDS.
// ---------------------------------------------------------------------------
__global__ __launch_bounds__(512, 2)
void gemm1_8ph(const __hip_bfloat16* __restrict__ A,
               const __hip_bfloat16* __restrict__ Bt,
               const float* __restrict__ bias,
               __hip_bfloat16* __restrict__ out,
               const int* __restrict__ total_ptr) {
  constexpr int K = SIXH;     // 1536
  constexpr int NT = K / 64;  // 24 K-tiles
  constexpr int N = FOURH;    // 1024

  extern __shared__ __align__(16) char lds[];

  int total = total_ptr[0];
  int padded = (total + 255) & ~255;
  int num_mt = padded >> 8;

  int bid = blockIdx.x;        // 0..255
  int xcd = bid & 7;
  int slot = bid >> 3;         // 0..31
  int nt = slot & 3;           // 0..3
  int mtb = slot >> 2;         // 0..7
  int n0 = nt * 256;

  int tid = threadIdx.x;
  int lane = tid & 63;
  int w = tid >> 6;
  int wave_m = w >> 2;
  int wave_n = w & 3;

  int r15 = lane & 15, g = lane >> 4;
  int slot_r = (((r15 & 1) << 2) | g) ^ (r15 >> 1);
  int lane_off = (r15 >> 1) * 128 + slot_r * 16;

  int s0 = (tid & 7) ^ ((tid >> 3) & 7);
  int scol = (s0 & 3) * 8;
  int row0 = ((tid >> 3) << 1) + (s0 >> 2);
  int ldst0 = w * 1024;

  float bv4[4];
#pragma unroll
  for (int ni = 0; ni < 4; ni++)
    bv4[ni] = bias[n0 + wave_n * 64 + ni * 16 + r15];

#define REGA(d, h) (lds + (d) * 65536 + (h) * 16384)
#define REGB(d, h) (lds + (d) * 65536 + 32768 + (h) * 16384)

#define STAGE(P, t0, kt, h, rb)                                                \
  do {                                                                         \
    __builtin_amdgcn_global_load_lds(                                          \
        (gbl_void*)((P) + (size_t)((t0) + row0) * K + (kt) * 64 + (h) * 32 +   \
                    scol),                                                     \
        (lds_void*)((rb) + ldst0), 16, 0, 0);                                  \
    __builtin_amdgcn_global_load_lds(                                          \
        (gbl_void*)((P) + (size_t)((t0) + row0 + 128) * K + (kt) * 64 +        \
                    (h) * 32 + scol),                                          \
        (lds_void*)((rb) + 8192 + ldst0), 16, 0, 0);                           \
  } while (0)

  for (int mt = xcd + 8 * mtb; mt < num_mt; mt += 64) {
    int m0 = mt * 256;

    f32x4 acc[8][4] = {};

    STAGE(A, m0, 0, 0, REGA(0, 0));
    STAGE(Bt, n0, 0, 0, REGB(0, 0));
    STAGE(A, m0, 0, 1, REGA(0, 1));
    STAGE(Bt, n0, 0, 1, REGB(0, 1));
    STAGE(A, m0, 1, 0, REGA(1, 0));
    STAGE(Bt, n0, 1, 0, REGB(1, 0));
    VMCNT4();
    ASM_BAR();

    for (int kt = 0; kt < NT; ++kt) {
      int d = kt & 1;
      int kc1 = (kt + 1 < NT) ? kt + 1 : NT - 1;
      int kc2 = (kt + 2 < NT) ? kt + 2 : NT - 1;
      char* A0 = REGA(d, 0); char* A1 = REGA(d, 1);
      char* B0 = REGB(d, 0); char* B1 = REGB(d, 1);
      char* An1 = REGA(d ^ 1, 1);
      char* Bn1 = REGB(d ^ 1, 1);

      short8 a[4], b[4];

      // ======== first half: kh0 (reads A0/B0; stages next-dbuf kh1) ========
#pragma unroll
      for (int ni = 0; ni < 4; ni++)
        b[ni] = *(const short8*)(B0 + (wave_n * 64 + ni * 16) * 64 + lane_off);
#pragma unroll
      for (int j = 0; j < 4; j++)
        a[j] = *(const short8*)(A0 + (wave_m * 128 + j * 16) * 64 + lane_off);
      STAGE(A, m0, kc1, 1, An1);
      __builtin_amdgcn_s_setprio(1);
#pragma unroll
      for (int j = 0; j < 4; j++)
#pragma unroll
        for (int ni = 0; ni < 4; ni++)
          acc[j][ni] = __builtin_amdgcn_mfma_f32_16x16x32_bf16(a[j], b[ni],
                                                               acc[j][ni], 0, 0, 0);
      __builtin_amdgcn_s_setprio(0);
#pragma unroll
      for (int j = 0; j < 4; j++)
        a[j] = *(const short8*)(A0 + (wave_m * 128 + (4 + j) * 16) * 64 + lane_off);
      STAGE(Bt, n0, kc1, 1, Bn1);
      __builtin_amdgcn_s_setprio(1);
#pragma unroll
      for (int j = 0; j < 4; j++)
#pragma unroll
        for (int ni = 0; ni < 4; ni++)
          acc[4 + j][ni] = __builtin_amdgcn_mfma_f32_16x16x32_bf16(
              a[j], b[ni], acc[4 + j][ni], 0, 0, 0);
      __builtin_amdgcn_s_setprio(0);
      ASM_BAR();  // bar_mid

      // ======== second half: kh1 (reads A1/B1; stages this-dbuf kh0) =======
#pragma unroll
      for (int ni = 0; ni < 4; ni++)
        b[ni] = *(const short8*)(B1 + (wave_n * 64 + ni * 16) * 64 + lane_off);
#pragma unroll
      for (int j = 0; j < 4; j++)
        a[j] = *(const short8*)(A1 + (wave_m * 128 + j * 16) * 64 + lane_off);
      STAGE(A, m0, kc2, 0, A0);
      __builtin_amdgcn_s_setprio(1);
#pragma unroll
      for (int j = 0; j < 4; j++)
#pragma unroll
        for (int ni = 0; ni < 4; ni++)
          acc[j][ni] = __builtin_amdgcn_mfma_f32_16x16x32_bf16(a[j], b[ni],
                                                               acc[j][ni], 0, 0, 0);
      __builtin_amdgcn_s_setprio(0);
#pragma unroll
      for (int j = 0; j < 4; j++)
        a[j] = *(const short8*)(A1 + (wave_m * 128 + (4 + j) * 16) * 64 + lane_off);
      STAGE(Bt, n0, kc2, 0, B0);
      __builtin_amdgcn_s_setprio(1);
#pragma unroll
      for (int j = 0; j < 4; j++)
#pragma unroll
        for (int ni = 0; ni < 4; ni++)
          acc[4 + j][ni] = __builtin_amdgcn_mfma_f32_16x16x32_bf16(
              a[j], b[ni], acc[4 + j][ni], 0, 0, 0);
      __builtin_amdgcn_s_setprio(0);
      VMCNT4();
      ASM_BAR();  // bar_end
    }
    VMCNT0();

    int r0 = g * 4;
#pragma unroll
    for (int mi = 0; mi < 8; mi++)
#pragma unroll
      for (int ni = 0; ni < 4; ni++) {
        int col = n0 + wave_n * 64 + ni * 16 + r15;
        float bv = bv4[ni];
#pragma unroll
        for (int r = 0; r < 4; r++) {
          int row = m0 + wave_m * 128 + mi * 16 + r0 + r;
          float v = acc[mi][ni][r] + bv;
          v = v / (1.0f + __expf(-v));  // silu
          out[(size_t)row * N + col] = __float2bfloat16(v);
        }
      }
  }
#undef STAGE
#undef REGA
#undef REGB
}

// ---------------------------------------------------------------------------
// GEMM2 wide: 128 rows x full N=256, 8 waves of 64x64,
// fused scatter epilogue into d_out.
// ---------------------------------------------------------------------------
__global__ __launch_bounds__(512, 2)
void gemm2_wide(const __hip_bfloat16* __restrict__ A,
                const __hip_bfloat16* __restrict__ Bt,
                const float* __restrict__ bias,
                const int* __restrict__ tpos,
                const float* __restrict__ pos_emb,
                float* __restrict__ out,
                const int* __restrict__ total_ptr) {
  constexpr int K = FOURH;  // 1024
  int m0 = blockIdx.x * 128;
  int total = total_ptr[0];
  int padded = (total + 127) & ~127;
  if (m0 >= padded) return;

  __shared__ __hip_bfloat16 As[128 * 64];  // 16KB
  __shared__ __hip_bfloat16 Bs[256 * 64];  // 32KB
  int tid = threadIdx.x;
  int lane = tid & 63, w = tid >> 6;
  int wave_m = w >> 2;  // 0..1
  int wave_n = w & 3;   // 0..3
  int wm = wave_m * 64, wn = wave_n * 64;

  int srow = lane >> 3;
  int scol = (lane & 7) * 8;
  int r15 = lane & 15, g = lane >> 4;

  f32x4 acc[4][4] = {};

  for (int k0 = 0; k0 < K; k0 += 64) {
#pragma unroll
    for (int i = 0; i < 2; i++) {
      int c = w * 2 + i;
      int row = c * 8 + srow;
      __builtin_amdgcn_global_load_lds(
          (gbl_void*)&A[(size_t)(m0 + row) * K + k0 + scol],
          (lds_void*)(As + c * 512), 16, 0, 0);
    }
#pragma unroll
    for (int i = 0; i < 4; i++) {
      int c = w * 4 + i;
      int row = c * 8 + srow;
      __builtin_amdgcn_global_load_lds(
          (gbl_void*)&Bt[(size_t)row * K + k0 + scol],
          (lds_void*)(Bs + c * 512), 16, 0, 0);
    }
    __syncthreads();
#pragma unroll
    for (int kk = 0; kk < 64; kk += 32) {
      short8 a[4], bb[4];
#pragma unroll
      for (int m = 0; m < 4; m++)
        a[m] = *(const short8*)&As[(wm + m * 16 + r15) * 64 + kk + 8 * g];
#pragma unroll
      for (int n = 0; n < 4; n++)
        bb[n] = *(const short8*)&Bs[(wn + n * 16 + r15) * 64 + kk + 8 * g];
#pragma unroll
      for (int m = 0; m < 4; m++)
#pragma unroll
        for (int n = 0; n < 4; n++)
          acc[m][n] = __builtin_amdgcn_mfma_f32_16x16x32_bf16(a[m], bb[n],
                                                              acc[m][n], 0, 0, 0);
    }
    __syncthreads();
  }

  int r0 = g * 4;
#pragma unroll
  for (int m = 0; m < 4; m++) {
#pragma unroll
    for (int r = 0; r < 4; r++) {
      int row = m0 + wm + m * 16 + r0 + r;
      if (row >= total) continue;
      int pa = tpos[row];
      if (pa < 0) continue;
      int p = pa & (MAXT - 1);
#pragma unroll
      for (int n = 0; n < 4; n++) {
        int col = wn + n * 16 + r15;
        float v = acc[m][n][r] + bias[col] + pos_emb[p * H_ + col];
        out[(size_t)pa * H_ + col] = v;
      }
    }
  }
}

// ---------------------------------------------------------------------------
// merge2: sep rows (sep_token + pos_emb), zero-fill empty positions, mm.
// ---------------------------------------------------------------------------
__global__ void merge2_kernel(const int* __restrict__ gids,
                              const int* __restrict__ lengths,
                              const float* __restrict__ sep_token,
                              const float* __restrict__ pos_emb,
                              float* __restrict__ out) {
  int b = blockIdx.x, t = threadIdx.x;
  __shared__ signed char src[MAXT];
  __shared__ int g[L_];
  __shared__ int sh_total;
  int len = lengths[b];
  src[t] = 0;
  for (int l = t; l < len; l += 256) g[l] = gids[b * L_ + l];
  __syncthreads();
  if (t == 0) {
    int nsep = 0;
    for (int l = 0; l + 1 < len; l++)
      if (g[l] != g[l + 1]) nsep++;
    int total = len + nsep;
    sh_total = total;
    int off = MAXT - total;
    int sb = 0;
    for (int l = 0; l < len; l++) {
      int ti = off + l + sb;
      if (ti >= 0) src[ti] = 2;
      if (l + 1 < len && g[l] != g[l + 1]) {
        if (ti + 1 >= 0) src[ti + 1] = 1;
        sb++;
      }
    }
  }
  __syncthreads();
  int total = sh_total;
  int mlen = min(total, MAXT);

  int q = t >> 6, lane = t & 63, c4 = lane * 4;
  float4 sep4 = *(const float4*)&sep_token[c4];
  float* orow = out + (size_t)b * MAXT * H_;
  for (int p0 = 0; p0 < MAXT; p0 += 4) {
    int p = p0 + q;
    int s = src[p];
    if (s == 2) continue;
    float4 v;
    if (s == 1) {
      float4 pe = *(const float4*)&pos_emb[p * H_ + c4];
      v.x = sep4.x + pe.x; v.y = sep4.y + pe.y;
      v.z = sep4.z + pe.z; v.w = sep4.w + pe.w;
    } else {
      v.x = 0.f; v.y = 0.f; v.z = 0.f; v.w = 0.f;
    }
    *(float4*)&orow[(size_t)p * H_ + c4] = v;
  }
  float* mm = out + (size_t)B_ * MAXT * H_;
  mm[b * MAXT + t] = (t >= MAXT - mlen) ? 1.0f : 0.0f;
}

// ---------------------------------------------------------------------------
// launch
// ---------------------------------------------------------------------------
extern "C" void kernel_launch(void* const* d_in, const int* in_sizes, int n_in,
                              void* d_out, int out_size, void* d_ws,
                              size_t ws_size, hipStream_t stream) {
  const int* tok0 = (const int*)d_in[0];
  const int* tok1 = (const int*)d_in[1];
  const int* tok2 = (const int*)d_in[2];
  const int* tok3 = (const int*)d_in[3];
  const int* tgap = (const int*)d_in[4];
  const int* gid  = (const int*)d_in[5];
  const int* lengths = (const int*)d_in[6];
  const float* token_emb = (const float*)d_in[7];
  const float* gamma = (const float*)d_in[8];
  const float* beta  = (const float*)d_in[9];
  const float* w1 = (const float*)d_in[10];
  const float* b1 = (const float*)d_in[11];
  const float* w2 = (const float*)d_in[12];
  const float* b2 = (const float*)d_in[13];
  const float* tg_emb = (const float*)d_in[14];
  const float* g_emb  = (const float*)d_in[15];
  const float* pos_emb = (const float*)d_in[16];
  const float* sep_tok = (const float*)d_in[17];

  // workspace layout (bytes) — R14/R12 layout:
  //   x     bf16 [<=51200][1536] @ 0          (157,286,400)
  //   h     bf16 [<=51200][1024] @ 157286400  (104,857,600)
  //   w1t   bf16 [1024][1536]    @ 262144000  (  3,145,728)
  //   w2t   bf16 [256][1024]     @ 265289728  (    524,288)
  //   offsets int[257]           @ 265814016  (      1,028)
  //   tpos  int  [<=51200]       @ 265815044  (    204,800)
  const size_t NEEDED = 266019844;
  if (ws_size < NEEDED) return;

  char* ws = (char*)d_ws;
  __hip_bfloat16* x = (__hip_bfloat16*)ws;
  __hip_bfloat16* h = (__hip_bfloat16*)(ws + 157286400);
  __hip_bfloat16* w1t = (__hip_bfloat16*)(ws + 262144000);
  __hip_bfloat16* w2t = (__hip_bfloat16*)(ws + 265289728);
  int* offsets = (int*)(ws + 265814016);
  int* tpos = (int*)(ws + 265815044);

  fused_pre_tr<<<2048, 256, 0, stream>>>(lengths, gid, offsets, tpos, x, w1,
                                         w1t, w2, w2t);

  embed_ln_kernel<<<dim3(L_, B_), 192, 0, stream>>>(
      tok0, tok1, tok2, tok3, tgap, gid, lengths, offsets, token_emb, tg_emb,
      g_emb, gamma, beta, x);

  hipFuncSetAttribute((const void*)gemm1_8ph,
                      hipFuncAttributeMaxDynamicSharedMemorySize, 131072);
  gemm1_8ph<<<256, 512, 131072, stream>>>(x, w1t, b1, h, offsets + B_);

  gemm2_wide<<<NPOS / 128, 512, 0, stream>>>(h, w2t, b2, tpos, pos_emb,
                                             (float*)d_out, offsets + B_);

  merge2_kernel<<<B_, 256, 0, stream>>>(gid, lengths, sep_tok, pos_emb,
                                        (float*)d_out);
}